// Round 3
// baseline (337.932 us; speedup 1.0000x reference)
//
#include <hip/hip_runtime.h>
#include <math.h>

#define NN 100000
#define NB 391          // ceil(NN/256) buckets of 256 nodes
#define BT 8192         // edges per binning tile
#define CAP 12288       // per-bucket LDS sort capacity (avg bucket ~8192)
#define SRC_HALF 50000  // src-node split point for phase-split aggregation

typedef float vfloat2 __attribute__((ext_vector_type(2)));
typedef short short8 __attribute__((ext_vector_type(8)));
typedef float floatx4 __attribute__((ext_vector_type(4)));

// float -> bf16 (RNE)
__device__ __forceinline__ unsigned short f2bf(float f) {
    unsigned int u = __float_as_uint(f);
    u += 0x7fffu + ((u >> 16) & 1u);
    return (unsigned short)(u >> 16);
}

// fp8 e4m3 (OCP on gfx950) encode/decode via HW cvt.
__device__ __forceinline__ unsigned char f2fp8(float f) {
    const int p = __builtin_amdgcn_cvt_pk_fp8_f32(f, f, 0, false);
    return (unsigned char)(p & 0xFF);
}
template <bool HI>
__device__ __forceinline__ vfloat2 fp8pk2(unsigned int w) {
    return __builtin_amdgcn_cvt_pk_f32_fp8((int)w, HI);
}

// ---------------------------------------------------------------------------
// MFMA dual MLP (layers 1-2): per block of NPB nodes,
//   y[n, 0..CL)  = h @ Wl          (fp8 out, contiguous 64B/32B rows)
//   z[n, 0..CR)  = h @ Wr + bias   (f32 out)
// h = FUSE_IN ? relu(in0 + in1) : in0, computed during staging.
// ---------------------------------------------------------------------------
template <int D_IN, int CL, int CR, int NPB, int FUSE_IN>
__global__ void __launch_bounds__(256)
mlp_mfma_kernel(const float* __restrict__ in0,
                const float* __restrict__ in1,
                const float* __restrict__ Wl,
                const float* __restrict__ Wr,
                const float* __restrict__ bias,
                unsigned char* __restrict__ yout,
                float* __restrict__ zout,
                int n_nodes) {
    constexpr int COLS = CL + CR;
    constexpr int CT = COLS / 16;      // col tiles
    constexpr int KT = D_IN / 32;      // k tiles
    constexpr int NT = NPB / 16;       // node tiles per block
    constexpr int KG = D_IN / 8;       // 8-elem k-groups per row
    __shared__ short sA[NT * KT * 64 * 8];
    __shared__ short sB[CT * KT * 64 * 8];
    __shared__ float sBias[CR];
    const int t = threadIdx.x;
    const int node0 = blockIdx.x * NPB;

    // ---- stage A: read 8 floats per task, write one 16B fragment slice ----
    for (int i = t; i < NPB * KG; i += 256) {
        const int nl = i / KG, kg = i % KG;
        const int n = node0 + nl;
        float v[8];
        if (n < n_nodes) {
            const float4* p = (const float4*)(in0 + (long long)n * D_IN + kg * 8);
            float4 a0 = p[0], a1 = p[1];
            if (FUSE_IN) {
                const float4* q = (const float4*)(in1 + (long long)n * D_IN + kg * 8);
                const float4 b0 = q[0], b1 = q[1];
                a0.x = fmaxf(a0.x + b0.x, 0.f); a0.y = fmaxf(a0.y + b0.y, 0.f);
                a0.z = fmaxf(a0.z + b0.z, 0.f); a0.w = fmaxf(a0.w + b0.w, 0.f);
                a1.x = fmaxf(a1.x + b1.x, 0.f); a1.y = fmaxf(a1.y + b1.y, 0.f);
                a1.z = fmaxf(a1.z + b1.z, 0.f); a1.w = fmaxf(a1.w + b1.w, 0.f);
            }
            v[0] = a0.x; v[1] = a0.y; v[2] = a0.z; v[3] = a0.w;
            v[4] = a1.x; v[5] = a1.y; v[6] = a1.z; v[7] = a1.w;
        } else {
#pragma unroll
            for (int j = 0; j < 8; ++j) v[j] = 0.f;
        }
        short8 s;
#pragma unroll
        for (int j = 0; j < 8; ++j) s[j] = (short)f2bf(v[j]);
        const int nt = nl >> 4, m = nl & 15, kt = kg >> 2, quad = kg & 3;
        ((short8*)sA)[(nt * KT + kt) * 64 + quad * 16 + m] = s;
    }
    // ---- stage B (fragment-major) + bias ----
    for (int i = t; i < CT * KT * 64; i += 256) {
        const int ct = i / (KT * 64);
        const int rem = i % (KT * 64);
        const int kt = rem / 64, L = rem % 64;
        const int c = ct * 16 + (L & 15);
        const int k0 = kt * 32 + (L >> 4) * 8;
        short8 s;
#pragma unroll
        for (int j = 0; j < 8; ++j) {
            const int k = k0 + j;
            const float w = (c < CL) ? Wl[k * CL + c] : Wr[k * CR + (c - CL)];
            s[j] = (short)f2bf(w);
        }
        ((short8*)sB)[i] = s;
    }
    for (int i = t; i < CR; i += 256) sBias[i] = bias[i];
    __syncthreads();

    // ---- MFMA compute: each of 4 waves handles NT/4 node tiles ----
    const int w = t >> 6, lane = t & 63;
    short8 Bf[CT][KT];
#pragma unroll
    for (int ct = 0; ct < CT; ++ct)
#pragma unroll
        for (int kt = 0; kt < KT; ++kt)
            Bf[ct][kt] = ((short8*)sB)[(ct * KT + kt) * 64 + lane];
    const int col = lane & 15, quad = lane >> 4;
#pragma unroll
    for (int nti = 0; nti < NT / 4; ++nti) {
        const int nt = w * (NT / 4) + nti;
        short8 A[KT];
#pragma unroll
        for (int kt = 0; kt < KT; ++kt)
            A[kt] = ((short8*)sA)[(nt * KT + kt) * 64 + lane];
        const int nodeb = node0 + nt * 16 + quad * 4;
#pragma unroll
        for (int ct = 0; ct < CT; ++ct) {
            floatx4 acc = {0.f, 0.f, 0.f, 0.f};
#pragma unroll
            for (int kt = 0; kt < KT; ++kt)
                acc = __builtin_amdgcn_mfma_f32_16x16x32_bf16(A[kt], Bf[ct][kt], acc, 0, 0, 0);
            const int gc = ct * 16 + col;
#pragma unroll
            for (int r = 0; r < 4; ++r) {
                const int node = nodeb + r;
                if (node < n_nodes) {
                    if (gc < CL) yout[(long long)node * CL + gc] = f2fp8(acc[r]);
                    else zout[(long long)node * CR + (gc - CL)] = acc[r] + sBias[gc - CL];
                }
            }
        }
    }
}

// ---------------------------------------------------------------------------
// Layer-3 MLP: one thread per node. h = relu(mean2+z2);
// y3[n] = h@W3l, z3[n] = h@W3r + b3.
// ---------------------------------------------------------------------------
template <int D_IN>
__global__ void __launch_bounds__(256)
mlp3_kernel(const float* __restrict__ mean,
            const float* __restrict__ z,
            const float* __restrict__ W3l,
            const float* __restrict__ W3r,
            const float* __restrict__ b3,
            float* __restrict__ y,
            float* __restrict__ z3, int n_nodes) {
    __shared__ float swl[D_IN], swr[D_IN];
    const int t = threadIdx.x;
    if (t < D_IN) { swl[t] = W3l[t]; swr[t] = W3r[t]; }
    __syncthreads();
    const int n = blockIdx.x * 256 + t;
    if (n >= n_nodes) return;
    const float4* pm = (const float4*)(mean + (long long)n * D_IN);
    const float4* pz = (const float4*)(z + (long long)n * D_IN);
    float accl = 0.f, accr = 0.f;
#pragma unroll
    for (int q = 0; q < D_IN / 4; ++q) {
        const float4 m4 = pm[q];
        const float4 z4 = pz[q];
        const float h0 = fmaxf(m4.x + z4.x, 0.f);
        const float h1 = fmaxf(m4.y + z4.y, 0.f);
        const float h2 = fmaxf(m4.z + z4.z, 0.f);
        const float h3 = fmaxf(m4.w + z4.w, 0.f);
        accl += h0 * swl[4 * q] + h1 * swl[4 * q + 1] + h2 * swl[4 * q + 2] + h3 * swl[4 * q + 3];
        accr += h0 * swr[4 * q] + h1 * swr[4 * q + 1] + h2 * swr[4 * q + 2] + h3 * swr[4 * q + 3];
    }
    y[n] = accl;
    z3[n] = accr + b3[0];
}

// ---------------------------------------------------------------------------
// bucket histogram
// ---------------------------------------------------------------------------
__global__ void bucket_hist_kernel(const int* __restrict__ dst,
                                   int* __restrict__ bcnt, int n_edges) {
    __shared__ int lh[NB];
    for (int i = threadIdx.x; i < NB; i += 256) lh[i] = 0;
    __syncthreads();
    const int stride = gridDim.x * 256;
    for (int i = blockIdx.x * 256 + threadIdx.x; i < n_edges; i += stride)
        atomicAdd(&lh[dst[i] >> 8], 1);
    __syncthreads();
    for (int i = threadIdx.x; i < NB; i += 256)
        if (lh[i]) atomicAdd(&bcnt[i], lh[i]);
}

// ---------------------------------------------------------------------------
// single-block scan: boffs = exclusive scan of bcnt; bcursor = boffs
// ---------------------------------------------------------------------------
__global__ void __launch_bounds__(512)
bucket_scan_kernel(const int* __restrict__ bcnt, int* __restrict__ boffs,
                   int* __restrict__ bcursor) {
    __shared__ int s[512];
    const int t = threadIdx.x;
    const int v = (t < NB) ? bcnt[t] : 0;
    s[t] = v;
    __syncthreads();
    for (int off = 1; off < 512; off <<= 1) {
        const int tmp = (t >= off) ? s[t - off] : 0;
        __syncthreads();
        s[t] += tmp;
        __syncthreads();
    }
    const int excl = s[t] - v;
    if (t <= NB) boffs[t] = excl;
    if (t < NB) bcursor[t] = excl;
}

// ---------------------------------------------------------------------------
// binning: pack edges (src | dstLocal<<17) grouped by 256-node dst bucket.
// ---------------------------------------------------------------------------
__global__ void __launch_bounds__(512)
bin_edges_kernel(const int* __restrict__ src, const int* __restrict__ dst,
                 int* __restrict__ bcursor, unsigned int* __restrict__ binned,
                 int n_edges) {
    __shared__ unsigned int stage[BT];
    __shared__ unsigned short sbkt[BT];
    __shared__ int lhist[512], lscan[512], lstart[512], gbase[512], lcur[512];
    const int t = threadIdx.x;
    const int e0 = blockIdx.x * BT;
    const int count = min(BT, n_edges - e0);
    lhist[t] = 0;
    __syncthreads();
    for (int i = t; i < count; i += 512) atomicAdd(&lhist[dst[e0 + i] >> 8], 1);
    __syncthreads();
    const int v = lhist[t];
    lscan[t] = v;
    __syncthreads();
    for (int off = 1; off < 512; off <<= 1) {
        const int tmp = (t >= off) ? lscan[t - off] : 0;
        __syncthreads();
        lscan[t] += tmp;
        __syncthreads();
    }
    const int excl = lscan[t] - v;
    lstart[t] = excl;
    lcur[t] = excl;
    if (t < NB && v > 0) gbase[t] = atomicAdd(&bcursor[t], v);
    __syncthreads();
    for (int i = t; i < count; i += 512) {
        const int d = dst[e0 + i];
        const int b = d >> 8;
        const int p = atomicAdd(&lcur[b], 1);
        stage[p] = (unsigned int)src[e0 + i] | ((unsigned int)(d & 255) << 17);
        sbkt[p] = (unsigned short)b;
    }
    __syncthreads();
    for (int i = t; i < count; i += 512) {
        const int b = sbkt[i];
        binned[gbase[b] + (i - lstart[b])] = stage[i];
    }
}

// ---------------------------------------------------------------------------
// per-bucket counting sort -> full CSR (ssrc, row_ptr, rowmid, inv_deg).
// Sort key = (dstLocal, src >= SRC_HALF) so each row's edges are partitioned
// into low-src then high-src; rowmid[n] marks the boundary. Enables the
// phase-split aggregation (each phase's gather working set = half the table).
// ---------------------------------------------------------------------------
__global__ void __launch_bounds__(1024)
csr_sort_kernel(const unsigned int* __restrict__ binned,
                const int* __restrict__ boffs,
                int* __restrict__ ssrc, int* __restrict__ row_ptr,
                int* __restrict__ rowmid, float* __restrict__ inv_deg,
                int n_nodes, int n_edges) {
    __shared__ int stage[CAP];
    __shared__ int hist[512];
    __shared__ int lincl[512];
    __shared__ int lcur[512];
    const int t = threadIdx.x;
    const int b = blockIdx.x;
    const int s0 = boffs[b], s1 = boffs[b + 1];
    const int count = s1 - s0;
    if (t < 512) hist[t] = 0;
    __syncthreads();
    for (int i = t; i < count; i += 1024) {
        const unsigned int v = binned[s0 + i];
        const int key = (int)((v >> 17) << 1) | ((v & 0x1FFFFu) >= SRC_HALF ? 1 : 0);
        atomicAdd(&hist[key], 1);
    }
    __syncthreads();
    if (t < 512) lincl[t] = hist[t];
    __syncthreads();
    for (int off = 1; off < 512; off <<= 1) {
        int tmp = 0;
        if (t < 512 && t >= off) tmp = lincl[t - off];
        __syncthreads();
        if (t < 512) lincl[t] += tmp;
        __syncthreads();
    }
    // lincl = inclusive scan over 512 keys
    if (t < 512) lcur[t] = lincl[t] - hist[t];   // exclusive start per key
    if (t < 256) {
        const int S = lincl[2 * t] - hist[2 * t];     // row start (excl)
        const int M = lincl[2 * t];                   // mid = end of low-src part
        const int En = lincl[2 * t + 1];              // row end (incl scan)
        const int n = (b << 8) + t;
        if (n < n_nodes) {
            row_ptr[n] = s0 + S;
            rowmid[n] = s0 + M;
            inv_deg[n] = 1.0f / (float)max(En - S, 1);
        }
    }
    if (b == NB - 1 && t == 0) row_ptr[n_nodes] = n_edges;
    __syncthreads();
    for (int i = t; i < count; i += 1024) {
        const unsigned int v = binned[s0 + i];
        const int key = (int)((v >> 17) << 1) | ((v & 0x1FFFFu) >= SRC_HALF ? 1 : 0);
        const int p = atomicAdd(&lcur[key], 1);
        if (p < CAP) stage[p] = (int)(v & 0x1FFFFu);
    }
    __syncthreads();
    for (int i = t; i < count; i += 1024) ssrc[s0 + i] = stage[i];
}

// ---------------------------------------------------------------------------
// PHASE-SPLIT gather-side mean over fp8 rows.
// PHASE 0: edges [row_ptr[n], rowmid[n])  -- src < SRC_HALF; writes raw sums.
// PHASE 1: edges [rowmid[n], row_ptr[n+1]) -- src >= SRC_HALF; reads partial,
//          adds, scales by inv_deg, writes final mean.
// Each phase's gather working set is half the table (3.2MB @ D=64, 1.6MB @
// D=32) -> fits per-XCD 4MB L2 for ALL XCDs simultaneously; request count
// per edge unchanged (one full-row 64B/32B read). EP edge-parallel teams +
// shfl combine as before. Streaming ssrc/partial traffic is non-temporal.
// ---------------------------------------------------------------------------
template <int D, int EP, int PHASE>
__global__ void __launch_bounds__(256)
agg_mean_fp8_phase_kernel(const unsigned int* __restrict__ yb,
                          const int* __restrict__ row_ptr,
                          const int* __restrict__ rowmid,
                          const int* __restrict__ ssrc,
                          const float* __restrict__ inv_deg,
                          float* __restrict__ mean, int n_nodes) {
    constexpr int G = D / 16;        // uint4 slices per row
    constexpr int TPN = EP * G;      // threads per node
    constexpr int NPB = 256 / TPN;   // nodes per block
    const int t = threadIdx.x;
    const int g = t / TPN;           // node within block
    const int sub = t % TPN;
    const int lane = sub % G;        // row slice
    const int team = sub / G;        // edge-chunk index
    const int n = blockIdx.x * NPB + g;
    if (n >= n_nodes) return;
    int s0, s1;
    if (PHASE == 0) { s0 = row_ptr[n]; s1 = rowmid[n]; }
    else            { s0 = rowmid[n];  s1 = row_ptr[n + 1]; }
    const int cnt = s1 - s0;
    const int b0 = s0 + (cnt * team) / EP;
    const int b1 = s0 + (cnt * (team + 1)) / EP;
    const uint4* yv = (const uint4*)yb;          // row stride = G uint4
    float acc[16];
#pragma unroll
    for (int i = 0; i < 16; ++i) acc[i] = 0.f;
    int e = b0;
    for (; e + 4 <= b1; e += 4) {
        int sidx[4];
#pragma unroll
        for (int q = 0; q < 4; ++q) sidx[q] = __builtin_nontemporal_load(ssrc + e + q);
        uint4 v[4];
#pragma unroll
        for (int q = 0; q < 4; ++q) v[q] = yv[(long long)sidx[q] * G + lane];
#pragma unroll
        for (int q = 0; q < 4; ++q) {
            const unsigned int wx = v[q].x, wy = v[q].y, wz = v[q].z, ww = v[q].w;
            vfloat2 p;
            p = fp8pk2<false>(wx); acc[0]  += p.x; acc[1]  += p.y;
            p = fp8pk2<true>(wx);  acc[2]  += p.x; acc[3]  += p.y;
            p = fp8pk2<false>(wy); acc[4]  += p.x; acc[5]  += p.y;
            p = fp8pk2<true>(wy);  acc[6]  += p.x; acc[7]  += p.y;
            p = fp8pk2<false>(wz); acc[8]  += p.x; acc[9]  += p.y;
            p = fp8pk2<true>(wz);  acc[10] += p.x; acc[11] += p.y;
            p = fp8pk2<false>(ww); acc[12] += p.x; acc[13] += p.y;
            p = fp8pk2<true>(ww);  acc[14] += p.x; acc[15] += p.y;
        }
    }
    for (; e < b1; ++e) {
        const int si = __builtin_nontemporal_load(ssrc + e);
        const uint4 v = yv[(long long)si * G + lane];
        vfloat2 p;
        p = fp8pk2<false>(v.x); acc[0]  += p.x; acc[1]  += p.y;
        p = fp8pk2<true>(v.x);  acc[2]  += p.x; acc[3]  += p.y;
        p = fp8pk2<false>(v.y); acc[4]  += p.x; acc[5]  += p.y;
        p = fp8pk2<true>(v.y);  acc[6]  += p.x; acc[7]  += p.y;
        p = fp8pk2<false>(v.z); acc[8]  += p.x; acc[9]  += p.y;
        p = fp8pk2<true>(v.z);  acc[10] += p.x; acc[11] += p.y;
        p = fp8pk2<false>(v.w); acc[12] += p.x; acc[13] += p.y;
        p = fp8pk2<true>(v.w);  acc[14] += p.x; acc[15] += p.y;
    }
    // combine EP team partials (TPN=8 divides 64 -> all teams in same wave)
#pragma unroll
    for (int o = G; o < TPN; o <<= 1)
#pragma unroll
        for (int i = 0; i < 16; ++i) acc[i] += __shfl_xor(acc[i], o, 64);
    if (team == 0) {
        floatx4* mv = (floatx4*)mean + (long long)n * (D / 4) + lane * 4;
        if (PHASE == 0) {
#pragma unroll
            for (int q = 0; q < 4; ++q) {
                floatx4 o = {acc[4 * q], acc[4 * q + 1], acc[4 * q + 2], acc[4 * q + 3]};
                __builtin_nontemporal_store(o, mv + q);
            }
        } else {
            const float inv = inv_deg[n];
#pragma unroll
            for (int q = 0; q < 4; ++q) {
                const floatx4 pr = __builtin_nontemporal_load(mv + q);
                floatx4 o = {(acc[4 * q] + pr.x) * inv, (acc[4 * q + 1] + pr.y) * inv,
                             (acc[4 * q + 2] + pr.z) * inv, (acc[4 * q + 3] + pr.w) * inv};
                __builtin_nontemporal_store(o, mv + q);
            }
        }
    }
}

// D == 1 (fp32): one wave per node, shuffle reduction; fused sigmoid epilogue.
__global__ void agg_mean_d1_sig_kernel(const float* __restrict__ y,
                                       const int* __restrict__ row_ptr,
                                       const int* __restrict__ ssrc,
                                       const float* __restrict__ inv_deg,
                                       const float* __restrict__ z3,
                                       float* __restrict__ out, int n_nodes) {
    const int wave = threadIdx.x >> 6;
    const int lane = threadIdx.x & 63;
    const int n = blockIdx.x * 4 + wave;
    if (n >= n_nodes) return;
    const int s0 = row_ptr[n], s1 = row_ptr[n + 1];
    float acc = 0.f;
    for (int e = s0 + lane; e < s1; e += 64)
        acc += y[__builtin_nontemporal_load(ssrc + e)];
    for (int off = 32; off > 0; off >>= 1) acc += __shfl_down(acc, off, 64);
    if (lane == 0) out[n] = 1.0f / (1.0f + expf(-(acc * inv_deg[n] + z3[n])));
}

extern "C" void kernel_launch(void* const* d_in, const int* in_sizes, int n_in,
                              void* d_out, int out_size, void* d_ws, size_t ws_size,
                              hipStream_t stream) {
    const float* x = (const float*)d_in[0];
    const int* edge_index = (const int*)d_in[1];
    const float* W1l = (const float*)d_in[2];
    const float* b1  = (const float*)d_in[3];
    const float* W1r = (const float*)d_in[4];
    const float* W2l = (const float*)d_in[5];
    const float* b2  = (const float*)d_in[6];
    const float* W2r = (const float*)d_in[7];
    const float* W3l = (const float*)d_in[8];
    const float* b3  = (const float*)d_in[9];
    const float* W3r = (const float*)d_in[10];
    float* out = (float*)d_out;

    const int E = in_sizes[1] / 2;
    const int* src = edge_index;
    const int* dst = edge_index + E;

    // floats: bufY[32N] | meanB[64N] | z1[64N] | z2[32N] | z3[N] | inv_deg[N]
    // ints:   bcnt[NB] | boffs[NB+1] | bcursor[NB] | row_ptr[N+1] | ssrc[E] | rowmid[N]
    // binned[E] aliases z1 (dead after csr_sort; z1 written by mlp1 afterwards)
    float* bufY    = (float*)d_ws;
    float* meanB   = bufY + 32LL * NN;
    float* z1      = meanB + 64LL * NN;
    float* z2      = z1 + 64LL * NN;
    float* z3      = z2 + 32LL * NN;
    float* inv_deg = z3 + NN;
    int* bcnt      = (int*)(inv_deg + NN);
    int* boffs     = bcnt + NB;
    int* bcursor   = boffs + NB + 1;
    int* row_ptr   = bcursor + NB;
    int* ssrc      = row_ptr + NN + 1;
    int* rowmid    = ssrc + E;
    unsigned int* binned = (unsigned int*)z1;

    const int ntiles = (E + BT - 1) / BT;

    // ---- build dst-sorted CSR (dst identical across all 3 layers) ----
    (void)hipMemsetAsync(bcnt, 0, NB * sizeof(int), stream);
    bucket_hist_kernel<<<512, 256, 0, stream>>>(dst, bcnt, E);
    bucket_scan_kernel<<<1, 512, 0, stream>>>(bcnt, boffs, bcursor);
    bin_edges_kernel<<<ntiles, 512, 0, stream>>>(src, dst, bcursor, binned, E);
    csr_sort_kernel<<<NB, 1024, 0, stream>>>(binned, boffs, ssrc, row_ptr, rowmid,
                                             inv_deg, NN, E);

    // ---- layer 1: y1 = x@W1l (fp8), z1 = x@W1r + b1 (MFMA) ----
    mlp_mfma_kernel<64, 64, 64, 128, 0><<<(NN + 127) / 128, 256, 0, stream>>>(
        x, nullptr, W1l, W1r, b1, (unsigned char*)bufY, z1, NN);
    // phase-split aggregation: D=64, G=4, EP=2 -> TPN=8, 32 nodes/block
    agg_mean_fp8_phase_kernel<64, 2, 0><<<(NN + 31) / 32, 256, 0, stream>>>(
        (const unsigned int*)bufY, row_ptr, rowmid, ssrc, inv_deg, meanB, NN);
    agg_mean_fp8_phase_kernel<64, 2, 1><<<(NN + 31) / 32, 256, 0, stream>>>(
        (const unsigned int*)bufY, row_ptr, rowmid, ssrc, inv_deg, meanB, NN);

    // ---- layer 2: h1 = relu(mean1+z1) fused; y2 fp8, z2 (MFMA) ----
    mlp_mfma_kernel<64, 32, 32, 128, 1><<<(NN + 127) / 128, 256, 0, stream>>>(
        meanB, z1, W2l, W2r, b2, (unsigned char*)bufY, z2, NN);
    // phase-split aggregation: D=32, G=2, EP=4 -> TPN=8, 32 nodes/block
    agg_mean_fp8_phase_kernel<32, 4, 0><<<(NN + 31) / 32, 256, 0, stream>>>(
        (const unsigned int*)bufY, row_ptr, rowmid, ssrc, inv_deg, meanB, NN);
    agg_mean_fp8_phase_kernel<32, 4, 1><<<(NN + 31) / 32, 256, 0, stream>>>(
        (const unsigned int*)bufY, row_ptr, rowmid, ssrc, inv_deg, meanB, NN);

    // ---- layer 3: h2 = relu(mean2+z2) fused; y3 f32, z3; sigmoid fused ----
    mlp3_kernel<32><<<(NN + 255) / 256, 256, 0, stream>>>(
        meanB, z2, W3l, W3r, b3, bufY, z3, NN);
    agg_mean_d1_sig_kernel<<<(NN + 3) / 4, 256, 0, stream>>>(
        bufY, row_ptr, ssrc, inv_deg, z3, out, NN);
}

// Round 5
// 319.205 us; speedup vs baseline: 1.0587x; 1.0587x over previous
//
#include <hip/hip_runtime.h>
#include <math.h>

#define NN 100000
#define NB 391          // ceil(NN/256) buckets of 256 nodes
#define BT 8192         // edges per binning tile
#define CAP 12288       // per-bucket LDS sort capacity (avg bucket ~8192)
#define SRC_Q 25000     // src quartile width: 4 soft phases of ~1.6MB working set

typedef float vfloat2 __attribute__((ext_vector_type(2)));
typedef short short8 __attribute__((ext_vector_type(8)));
typedef float floatx4 __attribute__((ext_vector_type(4)));

// float -> bf16 (RNE)
__device__ __forceinline__ unsigned short f2bf(float f) {
    unsigned int u = __float_as_uint(f);
    u += 0x7fffu + ((u >> 16) & 1u);
    return (unsigned short)(u >> 16);
}

// fp8 e4m3 (OCP on gfx950) encode/decode via HW cvt.
__device__ __forceinline__ unsigned char f2fp8(float f) {
    const int p = __builtin_amdgcn_cvt_pk_fp8_f32(f, f, 0, false);
    return (unsigned char)(p & 0xFF);
}
template <bool HI>
__device__ __forceinline__ vfloat2 fp8pk2(unsigned int w) {
    return __builtin_amdgcn_cvt_pk_f32_fp8((int)w, HI);
}

// ---------------------------------------------------------------------------
// MFMA dual MLP (layers 1-2): per block of NPB nodes,
//   y[n, 0..CL)  = h @ Wl          (fp8 out, contiguous 64B/32B rows)
//   z[n, 0..CR)  = h @ Wr + bias   (f32 out)
// h = FUSE_IN ? relu(in0 + in1) : in0, computed during staging.
// ---------------------------------------------------------------------------
template <int D_IN, int CL, int CR, int NPB, int FUSE_IN>
__global__ void __launch_bounds__(256)
mlp_mfma_kernel(const float* __restrict__ in0,
                const float* __restrict__ in1,
                const float* __restrict__ Wl,
                const float* __restrict__ Wr,
                const float* __restrict__ bias,
                unsigned char* __restrict__ yout,
                float* __restrict__ zout,
                int n_nodes) {
    constexpr int COLS = CL + CR;
    constexpr int CT = COLS / 16;      // col tiles
    constexpr int KT = D_IN / 32;      // k tiles
    constexpr int NT = NPB / 16;       // node tiles per block
    constexpr int KG = D_IN / 8;       // 8-elem k-groups per row
    __shared__ short sA[NT * KT * 64 * 8];
    __shared__ short sB[CT * KT * 64 * 8];
    __shared__ float sBias[CR];
    const int t = threadIdx.x;
    const int node0 = blockIdx.x * NPB;

    // ---- stage A: read 8 floats per task, write one 16B fragment slice ----
    for (int i = t; i < NPB * KG; i += 256) {
        const int nl = i / KG, kg = i % KG;
        const int n = node0 + nl;
        float v[8];
        if (n < n_nodes) {
            const float4* p = (const float4*)(in0 + (long long)n * D_IN + kg * 8);
            float4 a0 = p[0], a1 = p[1];
            if (FUSE_IN) {
                const float4* q = (const float4*)(in1 + (long long)n * D_IN + kg * 8);
                const float4 b0 = q[0], b1 = q[1];
                a0.x = fmaxf(a0.x + b0.x, 0.f); a0.y = fmaxf(a0.y + b0.y, 0.f);
                a0.z = fmaxf(a0.z + b0.z, 0.f); a0.w = fmaxf(a0.w + b0.w, 0.f);
                a1.x = fmaxf(a1.x + b1.x, 0.f); a1.y = fmaxf(a1.y + b1.y, 0.f);
                a1.z = fmaxf(a1.z + b1.z, 0.f); a1.w = fmaxf(a1.w + b1.w, 0.f);
            }
            v[0] = a0.x; v[1] = a0.y; v[2] = a0.z; v[3] = a0.w;
            v[4] = a1.x; v[5] = a1.y; v[6] = a1.z; v[7] = a1.w;
        } else {
#pragma unroll
            for (int j = 0; j < 8; ++j) v[j] = 0.f;
        }
        short8 s;
#pragma unroll
        for (int j = 0; j < 8; ++j) s[j] = (short)f2bf(v[j]);
        const int nt = nl >> 4, m = nl & 15, kt = kg >> 2, quad = kg & 3;
        ((short8*)sA)[(nt * KT + kt) * 64 + quad * 16 + m] = s;
    }
    // ---- stage B (fragment-major) + bias ----
    for (int i = t; i < CT * KT * 64; i += 256) {
        const int ct = i / (KT * 64);
        const int rem = i % (KT * 64);
        const int kt = rem / 64, L = rem % 64;
        const int c = ct * 16 + (L & 15);
        const int k0 = kt * 32 + (L >> 4) * 8;
        short8 s;
#pragma unroll
        for (int j = 0; j < 8; ++j) {
            const int k = k0 + j;
            const float w = (c < CL) ? Wl[k * CL + c] : Wr[k * CR + (c - CL)];
            s[j] = (short)f2bf(w);
        }
        ((short8*)sB)[i] = s;
    }
    for (int i = t; i < CR; i += 256) sBias[i] = bias[i];
    __syncthreads();

    // ---- MFMA compute: each of 4 waves handles NT/4 node tiles ----
    const int w = t >> 6, lane = t & 63;
    short8 Bf[CT][KT];
#pragma unroll
    for (int ct = 0; ct < CT; ++ct)
#pragma unroll
        for (int kt = 0; kt < KT; ++kt)
            Bf[ct][kt] = ((short8*)sB)[(ct * KT + kt) * 64 + lane];
    const int col = lane & 15, quad = lane >> 4;
#pragma unroll
    for (int nti = 0; nti < NT / 4; ++nti) {
        const int nt = w * (NT / 4) + nti;
        short8 A[KT];
#pragma unroll
        for (int kt = 0; kt < KT; ++kt)
            A[kt] = ((short8*)sA)[(nt * KT + kt) * 64 + lane];
        const int nodeb = node0 + nt * 16 + quad * 4;
#pragma unroll
        for (int ct = 0; ct < CT; ++ct) {
            floatx4 acc = {0.f, 0.f, 0.f, 0.f};
#pragma unroll
            for (int kt = 0; kt < KT; ++kt)
                acc = __builtin_amdgcn_mfma_f32_16x16x32_bf16(A[kt], Bf[ct][kt], acc, 0, 0, 0);
            const int gc = ct * 16 + col;
#pragma unroll
            for (int r = 0; r < 4; ++r) {
                const int node = nodeb + r;
                if (node < n_nodes) {
                    if (gc < CL) yout[(long long)node * CL + gc] = f2fp8(acc[r]);
                    else zout[(long long)node * CR + (gc - CL)] = acc[r] + sBias[gc - CL];
                }
            }
        }
    }
}

// ---------------------------------------------------------------------------
// Layer-3 MLP: one thread per node. h = relu(mean2+z2);
// y3[n] = h@W3l, z3[n] = h@W3r + b3.
// ---------------------------------------------------------------------------
template <int D_IN>
__global__ void __launch_bounds__(256)
mlp3_kernel(const float* __restrict__ mean,
            const float* __restrict__ z,
            const float* __restrict__ W3l,
            const float* __restrict__ W3r,
            const float* __restrict__ b3,
            float* __restrict__ y,
            float* __restrict__ z3, int n_nodes) {
    __shared__ float swl[D_IN], swr[D_IN];
    const int t = threadIdx.x;
    if (t < D_IN) { swl[t] = W3l[t]; swr[t] = W3r[t]; }
    __syncthreads();
    const int n = blockIdx.x * 256 + t;
    if (n >= n_nodes) return;
    const float4* pm = (const float4*)(mean + (long long)n * D_IN);
    const float4* pz = (const float4*)(z + (long long)n * D_IN);
    float accl = 0.f, accr = 0.f;
#pragma unroll
    for (int q = 0; q < D_IN / 4; ++q) {
        const float4 m4 = pm[q];
        const float4 z4 = pz[q];
        const float h0 = fmaxf(m4.x + z4.x, 0.f);
        const float h1 = fmaxf(m4.y + z4.y, 0.f);
        const float h2 = fmaxf(m4.z + z4.z, 0.f);
        const float h3 = fmaxf(m4.w + z4.w, 0.f);
        accl += h0 * swl[4 * q] + h1 * swl[4 * q + 1] + h2 * swl[4 * q + 2] + h3 * swl[4 * q + 3];
        accr += h0 * swr[4 * q] + h1 * swr[4 * q + 1] + h2 * swr[4 * q + 2] + h3 * swr[4 * q + 3];
    }
    y[n] = accl;
    z3[n] = accr + b3[0];
}

// ---------------------------------------------------------------------------
// bucket histogram
// ---------------------------------------------------------------------------
__global__ void bucket_hist_kernel(const int* __restrict__ dst,
                                   int* __restrict__ bcnt, int n_edges) {
    __shared__ int lh[NB];
    for (int i = threadIdx.x; i < NB; i += 256) lh[i] = 0;
    __syncthreads();
    const int stride = gridDim.x * 256;
    for (int i = blockIdx.x * 256 + threadIdx.x; i < n_edges; i += stride)
        atomicAdd(&lh[dst[i] >> 8], 1);
    __syncthreads();
    for (int i = threadIdx.x; i < NB; i += 256)
        if (lh[i]) atomicAdd(&bcnt[i], lh[i]);
}

// ---------------------------------------------------------------------------
// single-block scan: boffs = exclusive scan of bcnt; bcursor = boffs
// ---------------------------------------------------------------------------
__global__ void __launch_bounds__(512)
bucket_scan_kernel(const int* __restrict__ bcnt, int* __restrict__ boffs,
                   int* __restrict__ bcursor) {
    __shared__ int s[512];
    const int t = threadIdx.x;
    const int v = (t < NB) ? bcnt[t] : 0;
    s[t] = v;
    __syncthreads();
    for (int off = 1; off < 512; off <<= 1) {
        const int tmp = (t >= off) ? s[t - off] : 0;
        __syncthreads();
        s[t] += tmp;
        __syncthreads();
    }
    const int excl = s[t] - v;
    if (t <= NB) boffs[t] = excl;
    if (t < NB) bcursor[t] = excl;
}

// ---------------------------------------------------------------------------
// binning: pack edges (src | dstLocal<<17) grouped by 256-node dst bucket.
// ---------------------------------------------------------------------------
__global__ void __launch_bounds__(512)
bin_edges_kernel(const int* __restrict__ src, const int* __restrict__ dst,
                 int* __restrict__ bcursor, unsigned int* __restrict__ binned,
                 int n_edges) {
    __shared__ unsigned int stage[BT];
    __shared__ unsigned short sbkt[BT];
    __shared__ int lhist[512], lscan[512], lstart[512], gbase[512], lcur[512];
    const int t = threadIdx.x;
    const int e0 = blockIdx.x * BT;
    const int count = min(BT, n_edges - e0);
    lhist[t] = 0;
    __syncthreads();
    for (int i = t; i < count; i += 512) atomicAdd(&lhist[dst[e0 + i] >> 8], 1);
    __syncthreads();
    const int v = lhist[t];
    lscan[t] = v;
    __syncthreads();
    for (int off = 1; off < 512; off <<= 1) {
        const int tmp = (t >= off) ? lscan[t - off] : 0;
        __syncthreads();
        lscan[t] += tmp;
        __syncthreads();
    }
    const int excl = lscan[t] - v;
    lstart[t] = excl;
    lcur[t] = excl;
    if (t < NB && v > 0) gbase[t] = atomicAdd(&bcursor[t], v);
    __syncthreads();
    for (int i = t; i < count; i += 512) {
        const int d = dst[e0 + i];
        const int b = d >> 8;
        const int p = atomicAdd(&lcur[b], 1);
        stage[p] = (unsigned int)src[e0 + i] | ((unsigned int)(d & 255) << 17);
        sbkt[p] = (unsigned short)b;
    }
    __syncthreads();
    for (int i = t; i < count; i += 512) {
        const int b = sbkt[i];
        binned[gbase[b] + (i - lstart[b])] = stage[i];
    }
}

// ---------------------------------------------------------------------------
// per-bucket counting sort -> full CSR (ssrc, row_ptr, inv_deg).
// Sort key = (dstLocal, src/SRC_Q): each row's edges are grouped into 4
// src-quarters. The gather kernel walks rows in order, so the co-resident
// grid's instantaneous working set is ~1 quarter of the fp8 table (1.6MB
// @ D=64) -> fits per-XCD 4MB L2 WITHOUT any barrier or partial round-trip
// (soft temporal phasing; ordering-only change, correctness-neutral).
// ---------------------------------------------------------------------------
__global__ void __launch_bounds__(1024)
csr_sort_kernel(const unsigned int* __restrict__ binned,
                const int* __restrict__ boffs,
                int* __restrict__ ssrc, int* __restrict__ row_ptr,
                float* __restrict__ inv_deg, int n_nodes, int n_edges) {
    __shared__ int stage[CAP];
    __shared__ int hist[1024];
    __shared__ int lincl[1024];
    __shared__ int lcur[1024];
    const int t = threadIdx.x;
    const int b = blockIdx.x;
    const int s0 = boffs[b], s1 = boffs[b + 1];
    const int count = s1 - s0;
    hist[t] = 0;
    __syncthreads();
    for (int i = t; i < count; i += 1024) {
        const unsigned int v = binned[s0 + i];
        const int key = (int)((v >> 17) << 2) | ((int)(v & 0x1FFFFu) / SRC_Q);
        atomicAdd(&hist[key], 1);
    }
    __syncthreads();
    lincl[t] = hist[t];
    __syncthreads();
    for (int off = 1; off < 1024; off <<= 1) {
        const int tmp = (t >= off) ? lincl[t - off] : 0;
        __syncthreads();
        lincl[t] += tmp;
        __syncthreads();
    }
    lcur[t] = lincl[t] - hist[t];
    if (t < 256) {
        const int S = lincl[4 * t] - hist[4 * t];     // row start (exclusive)
        const int En = lincl[4 * t + 3];              // row end (inclusive)
        const int n = (b << 8) + t;
        if (n < n_nodes) {
            row_ptr[n] = s0 + S;
            inv_deg[n] = 1.0f / (float)max(En - S, 1);
        }
    }
    if (b == NB - 1 && t == 0) row_ptr[n_nodes] = n_edges;
    __syncthreads();
    for (int i = t; i < count; i += 1024) {
        const unsigned int v = binned[s0 + i];
        const int key = (int)((v >> 17) << 2) | ((int)(v & 0x1FFFFu) / SRC_Q);
        const int p = atomicAdd(&lcur[key], 1);
        if (p < CAP) stage[p] = (int)(v & 0x1FFFFu);
    }
    __syncthreads();
    for (int i = t; i < count; i += 1024) ssrc[s0 + i] = stage[i];
}

// ---------------------------------------------------------------------------
// gather-side mean over fp8 rows. One team of G=D/16 lanes per node walks
// the row IN ORDER (src-quarter sorted) -> soft-phased gather working set.
// ssrc loads / mean stores non-temporal to protect the L2-resident table.
// ---------------------------------------------------------------------------
template <int D>
__global__ void __launch_bounds__(256)
agg_mean_fp8_kernel(const unsigned int* __restrict__ yb,
                    const int* __restrict__ row_ptr,
                    const int* __restrict__ ssrc,
                    const float* __restrict__ inv_deg,
                    float* __restrict__ mean, int n_nodes) {
    constexpr int G = D / 16;        // uint4 slices per row
    constexpr int NPB = 256 / G;     // nodes per block
    const int g = threadIdx.x / G;
    const int lane = threadIdx.x % G;
    const int n = blockIdx.x * NPB + g;
    if (n >= n_nodes) return;
    const int s0 = row_ptr[n], s1 = row_ptr[n + 1];
    const uint4* yv = (const uint4*)yb;          // row stride = G uint4
    float acc[16];
#pragma unroll
    for (int i = 0; i < 16; ++i) acc[i] = 0.f;
    int e = s0;
    for (; e + 4 <= s1; e += 4) {
        int sidx[4];
#pragma unroll
        for (int q = 0; q < 4; ++q) sidx[q] = __builtin_nontemporal_load(ssrc + e + q);
        uint4 v[4];
#pragma unroll
        for (int q = 0; q < 4; ++q) v[q] = yv[(long long)sidx[q] * G + lane];
#pragma unroll
        for (int q = 0; q < 4; ++q) {
            const unsigned int wx = v[q].x, wy = v[q].y, wz = v[q].z, ww = v[q].w;
            vfloat2 p;
            p = fp8pk2<false>(wx); acc[0]  += p.x; acc[1]  += p.y;
            p = fp8pk2<true>(wx);  acc[2]  += p.x; acc[3]  += p.y;
            p = fp8pk2<false>(wy); acc[4]  += p.x; acc[5]  += p.y;
            p = fp8pk2<true>(wy);  acc[6]  += p.x; acc[7]  += p.y;
            p = fp8pk2<false>(wz); acc[8]  += p.x; acc[9]  += p.y;
            p = fp8pk2<true>(wz);  acc[10] += p.x; acc[11] += p.y;
            p = fp8pk2<false>(ww); acc[12] += p.x; acc[13] += p.y;
            p = fp8pk2<true>(ww);  acc[14] += p.x; acc[15] += p.y;
        }
    }
    for (; e < s1; ++e) {
        const int si = __builtin_nontemporal_load(ssrc + e);
        const uint4 v = yv[(long long)si * G + lane];
        vfloat2 p;
        p = fp8pk2<false>(v.x); acc[0]  += p.x; acc[1]  += p.y;
        p = fp8pk2<true>(v.x);  acc[2]  += p.x; acc[3]  += p.y;
        p = fp8pk2<false>(v.y); acc[4]  += p.x; acc[5]  += p.y;
        p = fp8pk2<true>(v.y);  acc[6]  += p.x; acc[7]  += p.y;
        p = fp8pk2<false>(v.z); acc[8]  += p.x; acc[9]  += p.y;
        p = fp8pk2<true>(v.z);  acc[10] += p.x; acc[11] += p.y;
        p = fp8pk2<false>(v.w); acc[12] += p.x; acc[13] += p.y;
        p = fp8pk2<true>(v.w);  acc[14] += p.x; acc[15] += p.y;
    }
    const float inv = inv_deg[n];
    floatx4* mv = (floatx4*)mean + (long long)n * (D / 4) + lane * 4;
#pragma unroll
    for (int q = 0; q < 4; ++q) {
        floatx4 o = {acc[4 * q] * inv, acc[4 * q + 1] * inv,
                     acc[4 * q + 2] * inv, acc[4 * q + 3] * inv};
        __builtin_nontemporal_store(o, mv + q);
    }
}

// D == 1 (fp32): one wave per node, shuffle reduction; fused sigmoid epilogue.
// y3 table is 400KB -> fully L2-resident; no phasing needed.
__global__ void agg_mean_d1_sig_kernel(const float* __restrict__ y,
                                       const int* __restrict__ row_ptr,
                                       const int* __restrict__ ssrc,
                                       const float* __restrict__ inv_deg,
                                       const float* __restrict__ z3,
                                       float* __restrict__ out, int n_nodes) {
    const int wave = threadIdx.x >> 6;
    const int lane = threadIdx.x & 63;
    const int n = blockIdx.x * 4 + wave;
    if (n >= n_nodes) return;
    const int s0 = row_ptr[n], s1 = row_ptr[n + 1];
    float acc = 0.f;
    for (int e = s0 + lane; e < s1; e += 64)
        acc += y[__builtin_nontemporal_load(ssrc + e)];
    for (int off = 32; off > 0; off >>= 1) acc += __shfl_down(acc, off, 64);
    if (lane == 0) out[n] = 1.0f / (1.0f + expf(-(acc * inv_deg[n] + z3[n])));
}

extern "C" void kernel_launch(void* const* d_in, const int* in_sizes, int n_in,
                              void* d_out, int out_size, void* d_ws, size_t ws_size,
                              hipStream_t stream) {
    const float* x = (const float*)d_in[0];
    const int* edge_index = (const int*)d_in[1];
    const float* W1l = (const float*)d_in[2];
    const float* b1  = (const float*)d_in[3];
    const float* W1r = (const float*)d_in[4];
    const float* W2l = (const float*)d_in[5];
    const float* b2  = (const float*)d_in[6];
    const float* W2r = (const float*)d_in[7];
    const float* W3l = (const float*)d_in[8];
    const float* b3  = (const float*)d_in[9];
    const float* W3r = (const float*)d_in[10];
    float* out = (float*)d_out;

    const int E = in_sizes[1] / 2;
    const int* src = edge_index;
    const int* dst = edge_index + E;

    // floats: bufY[32N] | meanB[64N] | z1[64N] | z2[32N] | z3[N] | inv_deg[N]
    // ints:   bcnt[NB] | boffs[NB+1] | bcursor[NB] | row_ptr[N+1] | ssrc[E]
    // binned[E] aliases z1 (dead after csr_sort; z1 written by mlp1 afterwards)
    float* bufY    = (float*)d_ws;
    float* meanB   = bufY + 32LL * NN;
    float* z1      = meanB + 64LL * NN;
    float* z2      = z1 + 64LL * NN;
    float* z3      = z2 + 32LL * NN;
    float* inv_deg = z3 + NN;
    int* bcnt      = (int*)(inv_deg + NN);
    int* boffs     = bcnt + NB;
    int* bcursor   = boffs + NB + 1;
    int* row_ptr   = bcursor + NB;
    int* ssrc      = row_ptr + NN + 1;
    unsigned int* binned = (unsigned int*)z1;

    const int ntiles = (E + BT - 1) / BT;

    // ---- build dst-sorted CSR (dst identical across all 3 layers) ----
    (void)hipMemsetAsync(bcnt, 0, NB * sizeof(int), stream);
    bucket_hist_kernel<<<512, 256, 0, stream>>>(dst, bcnt, E);
    bucket_scan_kernel<<<1, 512, 0, stream>>>(bcnt, boffs, bcursor);
    bin_edges_kernel<<<ntiles, 512, 0, stream>>>(src, dst, bcursor, binned, E);
    csr_sort_kernel<<<NB, 1024, 0, stream>>>(binned, boffs, ssrc, row_ptr,
                                             inv_deg, NN, E);

    // ---- layer 1: y1 = x@W1l (fp8), z1 = x@W1r + b1 (MFMA) ----
    mlp_mfma_kernel<64, 64, 64, 128, 0><<<(NN + 127) / 128, 256, 0, stream>>>(
        x, nullptr, W1l, W1r, b1, (unsigned char*)bufY, z1, NN);
    // D=64: G=4 -> 64 nodes/block, 1563 blocks (all co-resident @ 48 VGPR)
    agg_mean_fp8_kernel<64><<<(NN + 63) / 64, 256, 0, stream>>>(
        (const unsigned int*)bufY, row_ptr, ssrc, inv_deg, meanB, NN);

    // ---- layer 2: h1 = relu(mean1+z1) fused; y2 fp8, z2 (MFMA) ----
    mlp_mfma_kernel<64, 32, 32, 128, 1><<<(NN + 127) / 128, 256, 0, stream>>>(
        meanB, z1, W2l, W2r, b2, (unsigned char*)bufY, z2, NN);
    // D=32: G=2 -> 128 nodes/block, 782 blocks
    agg_mean_fp8_kernel<32><<<(NN + 127) / 128, 256, 0, stream>>>(
        (const unsigned int*)bufY, row_ptr, ssrc, inv_deg, meanB, NN);

    // ---- layer 3: h2 = relu(mean2+z2) fused; y3 f32, z3; sigmoid fused ----
    mlp3_kernel<32><<<(NN + 255) / 256, 256, 0, stream>>>(
        meanB, z2, W3l, W3r, b3, bufY, z3, NN);
    agg_mean_d1_sig_kernel<<<(NN + 3) / 4, 256, 0, stream>>>(
        bufY, row_ptr, ssrc, inv_deg, z3, out, NN);
}

// Round 6
// 305.520 us; speedup vs baseline: 1.1061x; 1.0448x over previous
//
#include <hip/hip_runtime.h>
#include <math.h>

#define NN 100000
#define NB 391          // ceil(NN/256) buckets of 256 nodes
#define BT 8192         // edges per binning tile
#define CAP 12288       // per-bucket LDS sort capacity (avg bucket ~8192)

typedef float vfloat2 __attribute__((ext_vector_type(2)));
typedef short short8 __attribute__((ext_vector_type(8)));
typedef float floatx4 __attribute__((ext_vector_type(4)));

// float -> bf16 (RNE)
__device__ __forceinline__ unsigned short f2bf(float f) {
    unsigned int u = __float_as_uint(f);
    u += 0x7fffu + ((u >> 16) & 1u);
    return (unsigned short)(u >> 16);
}

// fp8 e4m3 (OCP on gfx950) encode/decode via HW cvt.
__device__ __forceinline__ unsigned char f2fp8(float f) {
    const int p = __builtin_amdgcn_cvt_pk_fp8_f32(f, f, 0, false);
    return (unsigned char)(p & 0xFF);
}
template <bool HI>
__device__ __forceinline__ vfloat2 fp8pk2(unsigned int w) {
    return __builtin_amdgcn_cvt_pk_f32_fp8((int)w, HI);
}

// ---------------------------------------------------------------------------
// MFMA dual MLP (layers 1-2): per block of NPB nodes,
//   y[n, 0..CL)  = h @ Wl          (fp8 out, contiguous 64B/32B rows)
//   z[n, 0..CR)  = h @ Wr + bias   (f32 out)
// h = FUSE_IN ? relu(in0 + in1) : in0, computed during staging.
// ---------------------------------------------------------------------------
template <int D_IN, int CL, int CR, int NPB, int FUSE_IN>
__global__ void __launch_bounds__(256)
mlp_mfma_kernel(const float* __restrict__ in0,
                const float* __restrict__ in1,
                const float* __restrict__ Wl,
                const float* __restrict__ Wr,
                const float* __restrict__ bias,
                unsigned char* __restrict__ yout,
                float* __restrict__ zout,
                int n_nodes) {
    constexpr int COLS = CL + CR;
    constexpr int CT = COLS / 16;      // col tiles
    constexpr int KT = D_IN / 32;      // k tiles
    constexpr int NT = NPB / 16;       // node tiles per block
    constexpr int KG = D_IN / 8;       // 8-elem k-groups per row
    __shared__ short sA[NT * KT * 64 * 8];
    __shared__ short sB[CT * KT * 64 * 8];
    __shared__ float sBias[CR];
    const int t = threadIdx.x;
    const int node0 = blockIdx.x * NPB;

    // ---- stage A: read 8 floats per task, write one 16B fragment slice ----
    for (int i = t; i < NPB * KG; i += 256) {
        const int nl = i / KG, kg = i % KG;
        const int n = node0 + nl;
        float v[8];
        if (n < n_nodes) {
            const float4* p = (const float4*)(in0 + (long long)n * D_IN + kg * 8);
            float4 a0 = p[0], a1 = p[1];
            if (FUSE_IN) {
                const float4* q = (const float4*)(in1 + (long long)n * D_IN + kg * 8);
                const float4 b0 = q[0], b1 = q[1];
                a0.x = fmaxf(a0.x + b0.x, 0.f); a0.y = fmaxf(a0.y + b0.y, 0.f);
                a0.z = fmaxf(a0.z + b0.z, 0.f); a0.w = fmaxf(a0.w + b0.w, 0.f);
                a1.x = fmaxf(a1.x + b1.x, 0.f); a1.y = fmaxf(a1.y + b1.y, 0.f);
                a1.z = fmaxf(a1.z + b1.z, 0.f); a1.w = fmaxf(a1.w + b1.w, 0.f);
            }
            v[0] = a0.x; v[1] = a0.y; v[2] = a0.z; v[3] = a0.w;
            v[4] = a1.x; v[5] = a1.y; v[6] = a1.z; v[7] = a1.w;
        } else {
#pragma unroll
            for (int j = 0; j < 8; ++j) v[j] = 0.f;
        }
        short8 s;
#pragma unroll
        for (int j = 0; j < 8; ++j) s[j] = (short)f2bf(v[j]);
        const int nt = nl >> 4, m = nl & 15, kt = kg >> 2, quad = kg & 3;
        ((short8*)sA)[(nt * KT + kt) * 64 + quad * 16 + m] = s;
    }
    // ---- stage B (fragment-major) + bias ----
    for (int i = t; i < CT * KT * 64; i += 256) {
        const int ct = i / (KT * 64);
        const int rem = i % (KT * 64);
        const int kt = rem / 64, L = rem % 64;
        const int c = ct * 16 + (L & 15);
        const int k0 = kt * 32 + (L >> 4) * 8;
        short8 s;
#pragma unroll
        for (int j = 0; j < 8; ++j) {
            const int k = k0 + j;
            const float w = (c < CL) ? Wl[k * CL + c] : Wr[k * CR + (c - CL)];
            s[j] = (short)f2bf(w);
        }
        ((short8*)sB)[i] = s;
    }
    for (int i = t; i < CR; i += 256) sBias[i] = bias[i];
    __syncthreads();

    // ---- MFMA compute: each of 4 waves handles NT/4 node tiles ----
    const int w = t >> 6, lane = t & 63;
    short8 Bf[CT][KT];
#pragma unroll
    for (int ct = 0; ct < CT; ++ct)
#pragma unroll
        for (int kt = 0; kt < KT; ++kt)
            Bf[ct][kt] = ((short8*)sB)[(ct * KT + kt) * 64 + lane];
    const int col = lane & 15, quad = lane >> 4;
#pragma unroll
    for (int nti = 0; nti < NT / 4; ++nti) {
        const int nt = w * (NT / 4) + nti;
        short8 A[KT];
#pragma unroll
        for (int kt = 0; kt < KT; ++kt)
            A[kt] = ((short8*)sA)[(nt * KT + kt) * 64 + lane];
        const int nodeb = node0 + nt * 16 + quad * 4;
#pragma unroll
        for (int ct = 0; ct < CT; ++ct) {
            floatx4 acc = {0.f, 0.f, 0.f, 0.f};
#pragma unroll
            for (int kt = 0; kt < KT; ++kt)
                acc = __builtin_amdgcn_mfma_f32_16x16x32_bf16(A[kt], Bf[ct][kt], acc, 0, 0, 0);
            const int gc = ct * 16 + col;
#pragma unroll
            for (int r = 0; r < 4; ++r) {
                const int node = nodeb + r;
                if (node < n_nodes) {
                    if (gc < CL) yout[(long long)node * CL + gc] = f2fp8(acc[r]);
                    else zout[(long long)node * CR + (gc - CL)] = acc[r] + sBias[gc - CL];
                }
            }
        }
    }
}

// ---------------------------------------------------------------------------
// Layer-3 MLP: one thread per node. h = relu(mean2+z2);
// y3[n] = h@W3l, z3[n] = h@W3r + b3.
// ---------------------------------------------------------------------------
template <int D_IN>
__global__ void __launch_bounds__(256)
mlp3_kernel(const float* __restrict__ mean,
            const float* __restrict__ z,
            const float* __restrict__ W3l,
            const float* __restrict__ W3r,
            const float* __restrict__ b3,
            float* __restrict__ y,
            float* __restrict__ z3, int n_nodes) {
    __shared__ float swl[D_IN], swr[D_IN];
    const int t = threadIdx.x;
    if (t < D_IN) { swl[t] = W3l[t]; swr[t] = W3r[t]; }
    __syncthreads();
    const int n = blockIdx.x * 256 + t;
    if (n >= n_nodes) return;
    const float4* pm = (const float4*)(mean + (long long)n * D_IN);
    const float4* pz = (const float4*)(z + (long long)n * D_IN);
    float accl = 0.f, accr = 0.f;
#pragma unroll
    for (int q = 0; q < D_IN / 4; ++q) {
        const float4 m4 = pm[q];
        const float4 z4 = pz[q];
        const float h0 = fmaxf(m4.x + z4.x, 0.f);
        const float h1 = fmaxf(m4.y + z4.y, 0.f);
        const float h2 = fmaxf(m4.z + z4.z, 0.f);
        const float h3 = fmaxf(m4.w + z4.w, 0.f);
        accl += h0 * swl[4 * q] + h1 * swl[4 * q + 1] + h2 * swl[4 * q + 2] + h3 * swl[4 * q + 3];
        accr += h0 * swr[4 * q] + h1 * swr[4 * q + 1] + h2 * swr[4 * q + 2] + h3 * swr[4 * q + 3];
    }
    y[n] = accl;
    z3[n] = accr + b3[0];
}

// ---------------------------------------------------------------------------
// bucket histogram
// ---------------------------------------------------------------------------
__global__ void bucket_hist_kernel(const int* __restrict__ dst,
                                   int* __restrict__ bcnt, int n_edges) {
    __shared__ int lh[NB];
    for (int i = threadIdx.x; i < NB; i += 256) lh[i] = 0;
    __syncthreads();
    const int stride = gridDim.x * 256;
    for (int i = blockIdx.x * 256 + threadIdx.x; i < n_edges; i += stride)
        atomicAdd(&lh[dst[i] >> 8], 1);
    __syncthreads();
    for (int i = threadIdx.x; i < NB; i += 256)
        if (lh[i]) atomicAdd(&bcnt[i], lh[i]);
}

// ---------------------------------------------------------------------------
// single-block scan: boffs = exclusive scan of bcnt; bcursor = boffs
// ---------------------------------------------------------------------------
__global__ void __launch_bounds__(512)
bucket_scan_kernel(const int* __restrict__ bcnt, int* __restrict__ boffs,
                   int* __restrict__ bcursor) {
    __shared__ int s[512];
    const int t = threadIdx.x;
    const int v = (t < NB) ? bcnt[t] : 0;
    s[t] = v;
    __syncthreads();
    for (int off = 1; off < 512; off <<= 1) {
        const int tmp = (t >= off) ? s[t - off] : 0;
        __syncthreads();
        s[t] += tmp;
        __syncthreads();
    }
    const int excl = s[t] - v;
    if (t <= NB) boffs[t] = excl;
    if (t < NB) bcursor[t] = excl;
}

// ---------------------------------------------------------------------------
// binning: pack edges (src | dstLocal<<17) grouped by 256-node dst bucket.
// ---------------------------------------------------------------------------
__global__ void __launch_bounds__(512)
bin_edges_kernel(const int* __restrict__ src, const int* __restrict__ dst,
                 int* __restrict__ bcursor, unsigned int* __restrict__ binned,
                 int n_edges) {
    __shared__ unsigned int stage[BT];
    __shared__ unsigned short sbkt[BT];
    __shared__ int lhist[512], lscan[512], lstart[512], gbase[512], lcur[512];
    const int t = threadIdx.x;
    const int e0 = blockIdx.x * BT;
    const int count = min(BT, n_edges - e0);
    lhist[t] = 0;
    __syncthreads();
    for (int i = t; i < count; i += 512) atomicAdd(&lhist[dst[e0 + i] >> 8], 1);
    __syncthreads();
    const int v = lhist[t];
    lscan[t] = v;
    __syncthreads();
    for (int off = 1; off < 512; off <<= 1) {
        const int tmp = (t >= off) ? lscan[t - off] : 0;
        __syncthreads();
        lscan[t] += tmp;
        __syncthreads();
    }
    const int excl = lscan[t] - v;
    lstart[t] = excl;
    lcur[t] = excl;
    if (t < NB && v > 0) gbase[t] = atomicAdd(&bcursor[t], v);
    __syncthreads();
    for (int i = t; i < count; i += 512) {
        const int d = dst[e0 + i];
        const int b = d >> 8;
        const int p = atomicAdd(&lcur[b], 1);
        stage[p] = (unsigned int)src[e0 + i] | ((unsigned int)(d & 255) << 17);
        sbkt[p] = (unsigned short)b;
    }
    __syncthreads();
    for (int i = t; i < count; i += 512) {
        const int b = sbkt[i];
        binned[gbase[b] + (i - lstart[b])] = stage[i];
    }
}

// ---------------------------------------------------------------------------
// per-bucket counting sort -> full CSR (ssrc, row_ptr, inv_deg).
// ---------------------------------------------------------------------------
__global__ void __launch_bounds__(1024)
csr_sort_kernel(const unsigned int* __restrict__ binned,
                const int* __restrict__ boffs,
                int* __restrict__ ssrc, int* __restrict__ row_ptr,
                float* __restrict__ inv_deg, int n_nodes, int n_edges) {
    __shared__ int stage[CAP];
    __shared__ int hist[256];
    __shared__ int lexcl[256];
    __shared__ int lcur[256];
    const int t = threadIdx.x;
    const int b = blockIdx.x;
    const int s0 = boffs[b], s1 = boffs[b + 1];
    const int count = s1 - s0;
    if (t < 256) hist[t] = 0;
    __syncthreads();
    for (int i = t; i < count; i += 1024)
        atomicAdd(&hist[binned[s0 + i] >> 17], 1);
    __syncthreads();
    if (t < 256) lexcl[t] = hist[t];
    __syncthreads();
    for (int off = 1; off < 256; off <<= 1) {
        int tmp = 0;
        if (t < 256 && t >= off) tmp = lexcl[t - off];
        __syncthreads();
        if (t < 256) lexcl[t] += tmp;
        __syncthreads();
    }
    if (t < 256) {
        const int excl = lexcl[t] - hist[t];
        lcur[t] = excl;
        const int n = (b << 8) + t;
        if (n < n_nodes) {
            row_ptr[n] = s0 + excl;
            inv_deg[n] = 1.0f / (float)max(hist[t], 1);
        }
    }
    if (b == NB - 1 && t == 0) row_ptr[n_nodes] = n_edges;
    __syncthreads();
    for (int i = t; i < count; i += 1024) {
        const unsigned int v = binned[s0 + i];
        const int p = atomicAdd(&lcur[v >> 17], 1);
        if (p < CAP) stage[p] = (int)(v & 0x1FFFFu);
    }
    __syncthreads();
    for (int i = t; i < count; i += 1024) ssrc[s0 + i] = stage[i];
}

// ---------------------------------------------------------------------------
// dequant-accumulate one 16-fp8 row slice into acc[16]
// ---------------------------------------------------------------------------
__device__ __forceinline__ void dq_acc(const uint4 v, float acc[16]) {
    vfloat2 p;
    p = fp8pk2<false>(v.x); acc[0]  += p.x; acc[1]  += p.y;
    p = fp8pk2<true>(v.x);  acc[2]  += p.x; acc[3]  += p.y;
    p = fp8pk2<false>(v.y); acc[4]  += p.x; acc[5]  += p.y;
    p = fp8pk2<true>(v.y);  acc[6]  += p.x; acc[7]  += p.y;
    p = fp8pk2<false>(v.z); acc[8]  += p.x; acc[9]  += p.y;
    p = fp8pk2<true>(v.z);  acc[10] += p.x; acc[11] += p.y;
    p = fp8pk2<false>(v.w); acc[12] += p.x; acc[13] += p.y;
    p = fp8pk2<true>(v.w);  acc[14] += p.x; acc[15] += p.y;
}

// ---------------------------------------------------------------------------
// gather-side mean over fp8 rows, EDGE-PARALLEL teams + 8-DEEP load stage.
// Row layout: contiguous D fp8 bytes; G = D/16 uint4 slices per row.
// Each node served by EP teams of G lanes; TPN = EP*G = 8 lanes/node.
// The 8-deep stage issues 8 independent row-gathers before any dequant,
// doubling per-wave outstanding gather instructions vs the old 4-deep
// pipeline (tests pipeline-depth vs per-CU-MSHR as the throughput limit).
// ssrc loads / mean stores non-temporal to protect the L2-resident table.
// ---------------------------------------------------------------------------
template <int D, int EP>
__global__ void __launch_bounds__(256)
agg_mean_fp8_kernel(const unsigned int* __restrict__ yb,
                    const int* __restrict__ row_ptr,
                    const int* __restrict__ ssrc,
                    const float* __restrict__ inv_deg,
                    float* __restrict__ mean, int n_nodes) {
    constexpr int G = D / 16;        // uint4 slices per row
    constexpr int TPN = EP * G;      // threads per node
    constexpr int NPB = 256 / TPN;   // nodes per block
    const int t = threadIdx.x;
    const int g = t / TPN;           // node within block
    const int sub = t % TPN;
    const int lane = sub % G;        // row slice
    const int team = sub / G;        // edge-chunk index
    const int n = blockIdx.x * NPB + g;
    if (n >= n_nodes) return;
    const int s0 = row_ptr[n], s1 = row_ptr[n + 1];
    const int cnt = s1 - s0;
    const int b0 = s0 + (cnt * team) / EP;
    const int b1 = s0 + (cnt * (team + 1)) / EP;
    const uint4* yv = (const uint4*)yb;          // row stride = G uint4
    float acc[16];
#pragma unroll
    for (int i = 0; i < 16; ++i) acc[i] = 0.f;
    int e = b0;
    for (; e + 8 <= b1; e += 8) {
        int sidx[8];
#pragma unroll
        for (int q = 0; q < 8; ++q) sidx[q] = __builtin_nontemporal_load(ssrc + e + q);
        uint4 v[8];
#pragma unroll
        for (int q = 0; q < 8; ++q) v[q] = yv[(long long)sidx[q] * G + lane];
#pragma unroll
        for (int q = 0; q < 8; ++q) dq_acc(v[q], acc);
    }
    for (; e + 4 <= b1; e += 4) {
        int sidx[4];
#pragma unroll
        for (int q = 0; q < 4; ++q) sidx[q] = __builtin_nontemporal_load(ssrc + e + q);
        uint4 v[4];
#pragma unroll
        for (int q = 0; q < 4; ++q) v[q] = yv[(long long)sidx[q] * G + lane];
#pragma unroll
        for (int q = 0; q < 4; ++q) dq_acc(v[q], acc);
    }
    for (; e < b1; ++e) {
        const int si = __builtin_nontemporal_load(ssrc + e);
        const uint4 v = yv[(long long)si * G + lane];
        dq_acc(v, acc);
    }
    // combine EP team partials (teams of the same node sit at lane offsets
    // G, 2G, ... within the same wave since TPN=8 divides 64)
#pragma unroll
    for (int o = G; o < TPN; o <<= 1)
#pragma unroll
        for (int i = 0; i < 16; ++i) acc[i] += __shfl_xor(acc[i], o, 64);
    if (team == 0) {
        const float inv = inv_deg[n];
        floatx4* mv = (floatx4*)mean + (long long)n * (D / 4) + lane * 4;
#pragma unroll
        for (int q = 0; q < 4; ++q) {
            floatx4 o = {acc[4 * q] * inv, acc[4 * q + 1] * inv,
                         acc[4 * q + 2] * inv, acc[4 * q + 3] * inv};
            __builtin_nontemporal_store(o, mv + q);
        }
    }
}

// D == 1 (fp32): one wave per node, shuffle reduction; fused sigmoid epilogue.
__global__ void agg_mean_d1_sig_kernel(const float* __restrict__ y,
                                       const int* __restrict__ row_ptr,
                                       const int* __restrict__ ssrc,
                                       const float* __restrict__ inv_deg,
                                       const float* __restrict__ z3,
                                       float* __restrict__ out, int n_nodes) {
    const int wave = threadIdx.x >> 6;
    const int lane = threadIdx.x & 63;
    const int n = blockIdx.x * 4 + wave;
    if (n >= n_nodes) return;
    const int s0 = row_ptr[n], s1 = row_ptr[n + 1];
    float acc = 0.f;
    for (int e = s0 + lane; e < s1; e += 64)
        acc += y[__builtin_nontemporal_load(ssrc + e)];
    for (int off = 32; off > 0; off >>= 1) acc += __shfl_down(acc, off, 64);
    if (lane == 0) out[n] = 1.0f / (1.0f + expf(-(acc * inv_deg[n] + z3[n])));
}

extern "C" void kernel_launch(void* const* d_in, const int* in_sizes, int n_in,
                              void* d_out, int out_size, void* d_ws, size_t ws_size,
                              hipStream_t stream) {
    const float* x = (const float*)d_in[0];
    const int* edge_index = (const int*)d_in[1];
    const float* W1l = (const float*)d_in[2];
    const float* b1  = (const float*)d_in[3];
    const float* W1r = (const float*)d_in[4];
    const float* W2l = (const float*)d_in[5];
    const float* b2  = (const float*)d_in[6];
    const float* W2r = (const float*)d_in[7];
    const float* W3l = (const float*)d_in[8];
    const float* b3  = (const float*)d_in[9];
    const float* W3r = (const float*)d_in[10];
    float* out = (float*)d_out;

    const int E = in_sizes[1] / 2;
    const int* src = edge_index;
    const int* dst = edge_index + E;

    // floats: bufY[32N] | meanB[64N] | z1[64N] | z2[32N] | z3[N] | inv_deg[N]
    // ints:   bcnt[NB] | boffs[NB+1] | bcursor[NB] | row_ptr[N+1] | ssrc[E]
    // binned[E] aliases z1 (dead after csr_sort; z1 written by mlp1 afterwards)
    float* bufY    = (float*)d_ws;
    float* meanB   = bufY + 32LL * NN;
    float* z1      = meanB + 64LL * NN;
    float* z2      = z1 + 64LL * NN;
    float* z3      = z2 + 32LL * NN;
    float* inv_deg = z3 + NN;
    int* bcnt      = (int*)(inv_deg + NN);
    int* boffs     = bcnt + NB;
    int* bcursor   = boffs + NB + 1;
    int* row_ptr   = bcursor + NB;
    int* ssrc      = row_ptr + NN + 1;
    unsigned int* binned = (unsigned int*)z1;

    const int ntiles = (E + BT - 1) / BT;

    // ---- build dst-sorted CSR (dst identical across all 3 layers) ----
    (void)hipMemsetAsync(bcnt, 0, NB * sizeof(int), stream);
    bucket_hist_kernel<<<512, 256, 0, stream>>>(dst, bcnt, E);
    bucket_scan_kernel<<<1, 512, 0, stream>>>(bcnt, boffs, bcursor);
    bin_edges_kernel<<<ntiles, 512, 0, stream>>>(src, dst, bcursor, binned, E);
    csr_sort_kernel<<<NB, 1024, 0, stream>>>(binned, boffs, ssrc, row_ptr, inv_deg, NN, E);

    // ---- layer 1: y1 = x@W1l (fp8), z1 = x@W1r + b1 (MFMA) ----
    mlp_mfma_kernel<64, 64, 64, 128, 0><<<(NN + 127) / 128, 256, 0, stream>>>(
        x, nullptr, W1l, W1r, b1, (unsigned char*)bufY, z1, NN);
    // D=64: G=4, EP=2 -> TPN=8, 32 nodes/block
    agg_mean_fp8_kernel<64, 2><<<(NN + 31) / 32, 256, 0, stream>>>(
        (const unsigned int*)bufY, row_ptr, ssrc, inv_deg, meanB, NN);

    // ---- layer 2: h1 = relu(mean1+z1) fused; y2 fp8, z2 (MFMA) ----
    mlp_mfma_kernel<64, 32, 32, 128, 1><<<(NN + 127) / 128, 256, 0, stream>>>(
        meanB, z1, W2l, W2r, b2, (unsigned char*)bufY, z2, NN);
    // D=32: G=2, EP=4 -> TPN=8, 32 nodes/block
    agg_mean_fp8_kernel<32, 4><<<(NN + 31) / 32, 256, 0, stream>>>(
        (const unsigned int*)bufY, row_ptr, ssrc, inv_deg, meanB, NN);

    // ---- layer 3: h2 = relu(mean2+z2) fused; y3 f32, z3; sigmoid fused ----
    mlp3_kernel<32><<<(NN + 255) / 256, 256, 0, stream>>>(
        meanB, z2, W3l, W3r, b3, bufY, z3, NN);
    agg_mean_d1_sig_kernel<<<(NN + 3) / 4, 256, 0, stream>>>(
        bufY, row_ptr, ssrc, inv_deg, z3, out, NN);
}

// Round 7
// 301.144 us; speedup vs baseline: 1.1222x; 1.0145x over previous
//
#include <hip/hip_runtime.h>
#include <math.h>

#define NN 100000
#define NB 391          // ceil(NN/256) buckets of 256 nodes
#define BT 8192         // edges per binning tile
#define CAP 12288       // per-bucket LDS sort capacity (avg bucket ~8192)

typedef float vfloat2 __attribute__((ext_vector_type(2)));
typedef short short8 __attribute__((ext_vector_type(8)));
typedef float floatx4 __attribute__((ext_vector_type(4)));

// float -> bf16 (RNE)
__device__ __forceinline__ unsigned short f2bf(float f) {
    unsigned int u = __float_as_uint(f);
    u += 0x7fffu + ((u >> 16) & 1u);
    return (unsigned short)(u >> 16);
}

// fp8 e4m3 (OCP on gfx950) encode/decode via HW cvt.
__device__ __forceinline__ unsigned char f2fp8(float f) {
    const int p = __builtin_amdgcn_cvt_pk_fp8_f32(f, f, 0, false);
    return (unsigned char)(p & 0xFF);
}
template <bool HI>
__device__ __forceinline__ vfloat2 fp8pk2(unsigned int w) {
    return __builtin_amdgcn_cvt_pk_f32_fp8((int)w, HI);
}

// ---------------------------------------------------------------------------
// MFMA dual MLP (layers 1-2): per block of NPB nodes,
//   y[n, 0..CL)  = h @ Wl          (fp8 out, contiguous 64B/32B rows)
//   z[n, 0..CR)  = h @ Wr + bias   (f32 out)
// h = FUSE_IN ? relu(in0 + in1) : in0, computed during staging.
// ---------------------------------------------------------------------------
template <int D_IN, int CL, int CR, int NPB, int FUSE_IN>
__global__ void __launch_bounds__(256)
mlp_mfma_kernel(const float* __restrict__ in0,
                const float* __restrict__ in1,
                const float* __restrict__ Wl,
                const float* __restrict__ Wr,
                const float* __restrict__ bias,
                unsigned char* __restrict__ yout,
                float* __restrict__ zout,
                int n_nodes) {
    constexpr int COLS = CL + CR;
    constexpr int CT = COLS / 16;      // col tiles
    constexpr int KT = D_IN / 32;      // k tiles
    constexpr int NT = NPB / 16;       // node tiles per block
    constexpr int KG = D_IN / 8;       // 8-elem k-groups per row
    __shared__ short sA[NT * KT * 64 * 8];
    __shared__ short sB[CT * KT * 64 * 8];
    __shared__ float sBias[CR];
    const int t = threadIdx.x;
    const int node0 = blockIdx.x * NPB;

    // ---- stage A: read 8 floats per task, write one 16B fragment slice ----
    for (int i = t; i < NPB * KG; i += 256) {
        const int nl = i / KG, kg = i % KG;
        const int n = node0 + nl;
        float v[8];
        if (n < n_nodes) {
            const float4* p = (const float4*)(in0 + (long long)n * D_IN + kg * 8);
            float4 a0 = p[0], a1 = p[1];
            if (FUSE_IN) {
                const float4* q = (const float4*)(in1 + (long long)n * D_IN + kg * 8);
                const float4 b0 = q[0], b1 = q[1];
                a0.x = fmaxf(a0.x + b0.x, 0.f); a0.y = fmaxf(a0.y + b0.y, 0.f);
                a0.z = fmaxf(a0.z + b0.z, 0.f); a0.w = fmaxf(a0.w + b0.w, 0.f);
                a1.x = fmaxf(a1.x + b1.x, 0.f); a1.y = fmaxf(a1.y + b1.y, 0.f);
                a1.z = fmaxf(a1.z + b1.z, 0.f); a1.w = fmaxf(a1.w + b1.w, 0.f);
            }
            v[0] = a0.x; v[1] = a0.y; v[2] = a0.z; v[3] = a0.w;
            v[4] = a1.x; v[5] = a1.y; v[6] = a1.z; v[7] = a1.w;
        } else {
#pragma unroll
            for (int j = 0; j < 8; ++j) v[j] = 0.f;
        }
        short8 s;
#pragma unroll
        for (int j = 0; j < 8; ++j) s[j] = (short)f2bf(v[j]);
        const int nt = nl >> 4, m = nl & 15, kt = kg >> 2, quad = kg & 3;
        ((short8*)sA)[(nt * KT + kt) * 64 + quad * 16 + m] = s;
    }
    // ---- stage B (fragment-major) + bias ----
    for (int i = t; i < CT * KT * 64; i += 256) {
        const int ct = i / (KT * 64);
        const int rem = i % (KT * 64);
        const int kt = rem / 64, L = rem % 64;
        const int c = ct * 16 + (L & 15);
        const int k0 = kt * 32 + (L >> 4) * 8;
        short8 s;
#pragma unroll
        for (int j = 0; j < 8; ++j) {
            const int k = k0 + j;
            const float w = (c < CL) ? Wl[k * CL + c] : Wr[k * CR + (c - CL)];
            s[j] = (short)f2bf(w);
        }
        ((short8*)sB)[i] = s;
    }
    for (int i = t; i < CR; i += 256) sBias[i] = bias[i];
    __syncthreads();

    // ---- MFMA compute: each of 4 waves handles NT/4 node tiles ----
    const int w = t >> 6, lane = t & 63;
    short8 Bf[CT][KT];
#pragma unroll
    for (int ct = 0; ct < CT; ++ct)
#pragma unroll
        for (int kt = 0; kt < KT; ++kt)
            Bf[ct][kt] = ((short8*)sB)[(ct * KT + kt) * 64 + lane];
    const int col = lane & 15, quad = lane >> 4;
#pragma unroll
    for (int nti = 0; nti < NT / 4; ++nti) {
        const int nt = w * (NT / 4) + nti;
        short8 A[KT];
#pragma unroll
        for (int kt = 0; kt < KT; ++kt)
            A[kt] = ((short8*)sA)[(nt * KT + kt) * 64 + lane];
        const int nodeb = node0 + nt * 16 + quad * 4;
#pragma unroll
        for (int ct = 0; ct < CT; ++ct) {
            floatx4 acc = {0.f, 0.f, 0.f, 0.f};
#pragma unroll
            for (int kt = 0; kt < KT; ++kt)
                acc = __builtin_amdgcn_mfma_f32_16x16x32_bf16(A[kt], Bf[ct][kt], acc, 0, 0, 0);
            const int gc = ct * 16 + col;
#pragma unroll
            for (int r = 0; r < 4; ++r) {
                const int node = nodeb + r;
                if (node < n_nodes) {
                    if (gc < CL) yout[(long long)node * CL + gc] = f2fp8(acc[r]);
                    else zout[(long long)node * CR + (gc - CL)] = acc[r] + sBias[gc - CL];
                }
            }
        }
    }
}

// ---------------------------------------------------------------------------
// Layer-3 MLP: one thread per node. h = relu(mean2+z2);
// y3[n] = h@W3l, z3[n] = h@W3r + b3.
// ---------------------------------------------------------------------------
template <int D_IN>
__global__ void __launch_bounds__(256)
mlp3_kernel(const float* __restrict__ mean,
            const float* __restrict__ z,
            const float* __restrict__ W3l,
            const float* __restrict__ W3r,
            const float* __restrict__ b3,
            float* __restrict__ y,
            float* __restrict__ z3, int n_nodes) {
    __shared__ float swl[D_IN], swr[D_IN];
    const int t = threadIdx.x;
    if (t < D_IN) { swl[t] = W3l[t]; swr[t] = W3r[t]; }
    __syncthreads();
    const int n = blockIdx.x * 256 + t;
    if (n >= n_nodes) return;
    const float4* pm = (const float4*)(mean + (long long)n * D_IN);
    const float4* pz = (const float4*)(z + (long long)n * D_IN);
    float accl = 0.f, accr = 0.f;
#pragma unroll
    for (int q = 0; q < D_IN / 4; ++q) {
        const float4 m4 = pm[q];
        const float4 z4 = pz[q];
        const float h0 = fmaxf(m4.x + z4.x, 0.f);
        const float h1 = fmaxf(m4.y + z4.y, 0.f);
        const float h2 = fmaxf(m4.z + z4.z, 0.f);
        const float h3 = fmaxf(m4.w + z4.w, 0.f);
        accl += h0 * swl[4 * q] + h1 * swl[4 * q + 1] + h2 * swl[4 * q + 2] + h3 * swl[4 * q + 3];
        accr += h0 * swr[4 * q] + h1 * swr[4 * q + 1] + h2 * swr[4 * q + 2] + h3 * swr[4 * q + 3];
    }
    y[n] = accl;
    z3[n] = accr + b3[0];
}

// ---------------------------------------------------------------------------
// bucket histogram
// ---------------------------------------------------------------------------
__global__ void bucket_hist_kernel(const int* __restrict__ dst,
                                   int* __restrict__ bcnt, int n_edges) {
    __shared__ int lh[NB];
    for (int i = threadIdx.x; i < NB; i += 256) lh[i] = 0;
    __syncthreads();
    const int stride = gridDim.x * 256;
    for (int i = blockIdx.x * 256 + threadIdx.x; i < n_edges; i += stride)
        atomicAdd(&lh[dst[i] >> 8], 1);
    __syncthreads();
    for (int i = threadIdx.x; i < NB; i += 256)
        if (lh[i]) atomicAdd(&bcnt[i], lh[i]);
}

// ---------------------------------------------------------------------------
// single-block scan: boffs = exclusive scan of bcnt; bcursor = boffs
// ---------------------------------------------------------------------------
__global__ void __launch_bounds__(512)
bucket_scan_kernel(const int* __restrict__ bcnt, int* __restrict__ boffs,
                   int* __restrict__ bcursor) {
    __shared__ int s[512];
    const int t = threadIdx.x;
    const int v = (t < NB) ? bcnt[t] : 0;
    s[t] = v;
    __syncthreads();
    for (int off = 1; off < 512; off <<= 1) {
        const int tmp = (t >= off) ? s[t - off] : 0;
        __syncthreads();
        s[t] += tmp;
        __syncthreads();
    }
    const int excl = s[t] - v;
    if (t <= NB) boffs[t] = excl;
    if (t < NB) bcursor[t] = excl;
}

// ---------------------------------------------------------------------------
// binning: pack edges (src | dstLocal<<17) grouped by 256-node dst bucket.
// ---------------------------------------------------------------------------
__global__ void __launch_bounds__(512)
bin_edges_kernel(const int* __restrict__ src, const int* __restrict__ dst,
                 int* __restrict__ bcursor, unsigned int* __restrict__ binned,
                 int n_edges) {
    __shared__ unsigned int stage[BT];
    __shared__ unsigned short sbkt[BT];
    __shared__ int lhist[512], lscan[512], lstart[512], gbase[512], lcur[512];
    const int t = threadIdx.x;
    const int e0 = blockIdx.x * BT;
    const int count = min(BT, n_edges - e0);
    lhist[t] = 0;
    __syncthreads();
    for (int i = t; i < count; i += 512) atomicAdd(&lhist[dst[e0 + i] >> 8], 1);
    __syncthreads();
    const int v = lhist[t];
    lscan[t] = v;
    __syncthreads();
    for (int off = 1; off < 512; off <<= 1) {
        const int tmp = (t >= off) ? lscan[t - off] : 0;
        __syncthreads();
        lscan[t] += tmp;
        __syncthreads();
    }
    const int excl = lscan[t] - v;
    lstart[t] = excl;
    lcur[t] = excl;
    if (t < NB && v > 0) gbase[t] = atomicAdd(&bcursor[t], v);
    __syncthreads();
    for (int i = t; i < count; i += 512) {
        const int d = dst[e0 + i];
        const int b = d >> 8;
        const int p = atomicAdd(&lcur[b], 1);
        stage[p] = (unsigned int)src[e0 + i] | ((unsigned int)(d & 255) << 17);
        sbkt[p] = (unsigned short)b;
    }
    __syncthreads();
    for (int i = t; i < count; i += 512) {
        const int b = sbkt[i];
        binned[gbase[b] + (i - lstart[b])] = stage[i];
    }
}

// ---------------------------------------------------------------------------
// per-bucket counting sort -> full CSR (ssrc, row_ptr, inv_deg).
// ---------------------------------------------------------------------------
__global__ void __launch_bounds__(1024)
csr_sort_kernel(const unsigned int* __restrict__ binned,
                const int* __restrict__ boffs,
                int* __restrict__ ssrc, int* __restrict__ row_ptr,
                float* __restrict__ inv_deg, int n_nodes, int n_edges) {
    __shared__ int stage[CAP];
    __shared__ int hist[256];
    __shared__ int lexcl[256];
    __shared__ int lcur[256];
    const int t = threadIdx.x;
    const int b = blockIdx.x;
    const int s0 = boffs[b], s1 = boffs[b + 1];
    const int count = s1 - s0;
    if (t < 256) hist[t] = 0;
    __syncthreads();
    for (int i = t; i < count; i += 1024)
        atomicAdd(&hist[binned[s0 + i] >> 17], 1);
    __syncthreads();
    if (t < 256) lexcl[t] = hist[t];
    __syncthreads();
    for (int off = 1; off < 256; off <<= 1) {
        int tmp = 0;
        if (t < 256 && t >= off) tmp = lexcl[t - off];
        __syncthreads();
        if (t < 256) lexcl[t] += tmp;
        __syncthreads();
    }
    if (t < 256) {
        const int excl = lexcl[t] - hist[t];
        lcur[t] = excl;
        const int n = (b << 8) + t;
        if (n < n_nodes) {
            row_ptr[n] = s0 + excl;
            inv_deg[n] = 1.0f / (float)max(hist[t], 1);
        }
    }
    if (b == NB - 1 && t == 0) row_ptr[n_nodes] = n_edges;
    __syncthreads();
    for (int i = t; i < count; i += 1024) {
        const unsigned int v = binned[s0 + i];
        const int p = atomicAdd(&lcur[v >> 17], 1);
        if (p < CAP) stage[p] = (int)(v & 0x1FFFFu);
    }
    __syncthreads();
    for (int i = t; i < count; i += 1024) ssrc[s0 + i] = stage[i];
}

// ---------------------------------------------------------------------------
// gather-side mean over fp8 rows, EDGE-PARALLEL teams.
// Row layout: contiguous D fp8 bytes; G = D/16 uint4 slices per row (one
// coalesced 64B/32B wave-segment per row read).
// Each node is served by EP teams of G lanes; team q aggregates a contiguous
// chunk of the node's edge list; partial sums combined via shfl_xor.
// At the measured latency x miss-concurrency wall (~60G req/s) this
// structure is request-count-optimal: exactly one line request per edge.
// ---------------------------------------------------------------------------
template <int D, int EP>
__global__ void __launch_bounds__(256)
agg_mean_fp8_kernel(const unsigned int* __restrict__ yb,
                    const int* __restrict__ row_ptr,
                    const int* __restrict__ ssrc,
                    const float* __restrict__ inv_deg,
                    float* __restrict__ mean, int n_nodes) {
    constexpr int G = D / 16;        // uint4 slices per row
    constexpr int TPN = EP * G;      // threads per node
    constexpr int NPB = 256 / TPN;   // nodes per block
    const int t = threadIdx.x;
    const int g = t / TPN;           // node within block
    const int sub = t % TPN;
    const int lane = sub % G;        // row slice
    const int team = sub / G;        // edge-chunk index
    const int n = blockIdx.x * NPB + g;
    if (n >= n_nodes) return;
    const int s0 = row_ptr[n], s1 = row_ptr[n + 1];
    const int cnt = s1 - s0;
    const int b0 = s0 + (cnt * team) / EP;
    const int b1 = s0 + (cnt * (team + 1)) / EP;
    const uint4* yv = (const uint4*)yb;          // row stride = G uint4
    float acc[16];
#pragma unroll
    for (int i = 0; i < 16; ++i) acc[i] = 0.f;
    int e = b0;
    for (; e + 4 <= b1; e += 4) {
        int sidx[4];
#pragma unroll
        for (int q = 0; q < 4; ++q) sidx[q] = __builtin_nontemporal_load(ssrc + e + q);
        uint4 v[4];
#pragma unroll
        for (int q = 0; q < 4; ++q) v[q] = yv[(long long)sidx[q] * G + lane];
#pragma unroll
        for (int q = 0; q < 4; ++q) {
            const unsigned int wx = v[q].x, wy = v[q].y, wz = v[q].z, ww = v[q].w;
            vfloat2 p;
            p = fp8pk2<false>(wx); acc[0]  += p.x; acc[1]  += p.y;
            p = fp8pk2<true>(wx);  acc[2]  += p.x; acc[3]  += p.y;
            p = fp8pk2<false>(wy); acc[4]  += p.x; acc[5]  += p.y;
            p = fp8pk2<true>(wy);  acc[6]  += p.x; acc[7]  += p.y;
            p = fp8pk2<false>(wz); acc[8]  += p.x; acc[9]  += p.y;
            p = fp8pk2<true>(wz);  acc[10] += p.x; acc[11] += p.y;
            p = fp8pk2<false>(ww); acc[12] += p.x; acc[13] += p.y;
            p = fp8pk2<true>(ww);  acc[14] += p.x; acc[15] += p.y;
        }
    }
    for (; e < b1; ++e) {
        const int si = __builtin_nontemporal_load(ssrc + e);
        const uint4 v = yv[(long long)si * G + lane];
        vfloat2 p;
        p = fp8pk2<false>(v.x); acc[0]  += p.x; acc[1]  += p.y;
        p = fp8pk2<true>(v.x);  acc[2]  += p.x; acc[3]  += p.y;
        p = fp8pk2<false>(v.y); acc[4]  += p.x; acc[5]  += p.y;
        p = fp8pk2<true>(v.y);  acc[6]  += p.x; acc[7]  += p.y;
        p = fp8pk2<false>(v.z); acc[8]  += p.x; acc[9]  += p.y;
        p = fp8pk2<true>(v.z);  acc[10] += p.x; acc[11] += p.y;
        p = fp8pk2<false>(v.w); acc[12] += p.x; acc[13] += p.y;
        p = fp8pk2<true>(v.w);  acc[14] += p.x; acc[15] += p.y;
    }
    // combine EP team partials (teams of the same node sit at lane offsets
    // G, 2G, ... within the same wave since TPN=8 divides 64)
#pragma unroll
    for (int o = G; o < TPN; o <<= 1)
#pragma unroll
        for (int i = 0; i < 16; ++i) acc[i] += __shfl_xor(acc[i], o, 64);
    if (team == 0) {
        const float inv = inv_deg[n];
        floatx4* mv = (floatx4*)mean + (long long)n * (D / 4) + lane * 4;
#pragma unroll
        for (int q = 0; q < 4; ++q) {
            floatx4 o = {acc[4 * q] * inv, acc[4 * q + 1] * inv,
                         acc[4 * q + 2] * inv, acc[4 * q + 3] * inv};
            __builtin_nontemporal_store(o, mv + q);
        }
    }
}

// D == 1 (fp32): one wave per node, shuffle reduction; fused sigmoid epilogue.
__global__ void agg_mean_d1_sig_kernel(const float* __restrict__ y,
                                       const int* __restrict__ row_ptr,
                                       const int* __restrict__ ssrc,
                                       const float* __restrict__ inv_deg,
                                       const float* __restrict__ z3,
                                       float* __restrict__ out, int n_nodes) {
    const int wave = threadIdx.x >> 6;
    const int lane = threadIdx.x & 63;
    const int n = blockIdx.x * 4 + wave;
    if (n >= n_nodes) return;
    const int s0 = row_ptr[n], s1 = row_ptr[n + 1];
    float acc = 0.f;
    for (int e = s0 + lane; e < s1; e += 64)
        acc += y[__builtin_nontemporal_load(ssrc + e)];
    for (int off = 32; off > 0; off >>= 1) acc += __shfl_down(acc, off, 64);
    if (lane == 0) out[n] = 1.0f / (1.0f + expf(-(acc * inv_deg[n] + z3[n])));
}

extern "C" void kernel_launch(void* const* d_in, const int* in_sizes, int n_in,
                              void* d_out, int out_size, void* d_ws, size_t ws_size,
                              hipStream_t stream) {
    const float* x = (const float*)d_in[0];
    const int* edge_index = (const int*)d_in[1];
    const float* W1l = (const float*)d_in[2];
    const float* b1  = (const float*)d_in[3];
    const float* W1r = (const float*)d_in[4];
    const float* W2l = (const float*)d_in[5];
    const float* b2  = (const float*)d_in[6];
    const float* W2r = (const float*)d_in[7];
    const float* W3l = (const float*)d_in[8];
    const float* b3  = (const float*)d_in[9];
    const float* W3r = (const float*)d_in[10];
    float* out = (float*)d_out;

    const int E = in_sizes[1] / 2;
    const int* src = edge_index;
    const int* dst = edge_index + E;

    // floats: bufY[32N] | meanB[64N] | z1[64N] | z2[32N] | z3[N] | inv_deg[N]
    // ints:   bcnt[NB] | boffs[NB+1] | bcursor[NB] | row_ptr[N+1] | ssrc[E]
    // binned[E] aliases z1 (dead after csr_sort; z1 written by mlp1 afterwards)
    float* bufY    = (float*)d_ws;
    float* meanB   = bufY + 32LL * NN;
    float* z1      = meanB + 64LL * NN;
    float* z2      = z1 + 64LL * NN;
    float* z3      = z2 + 32LL * NN;
    float* inv_deg = z3 + NN;
    int* bcnt      = (int*)(inv_deg + NN);
    int* boffs     = bcnt + NB;
    int* bcursor   = boffs + NB + 1;
    int* row_ptr   = bcursor + NB;
    int* ssrc      = row_ptr + NN + 1;
    unsigned int* binned = (unsigned int*)z1;

    const int ntiles = (E + BT - 1) / BT;

    // ---- build dst-sorted CSR (dst identical across all 3 layers) ----
    (void)hipMemsetAsync(bcnt, 0, NB * sizeof(int), stream);
    bucket_hist_kernel<<<512, 256, 0, stream>>>(dst, bcnt, E);
    bucket_scan_kernel<<<1, 512, 0, stream>>>(bcnt, boffs, bcursor);
    bin_edges_kernel<<<ntiles, 512, 0, stream>>>(src, dst, bcursor, binned, E);
    csr_sort_kernel<<<NB, 1024, 0, stream>>>(binned, boffs, ssrc, row_ptr, inv_deg, NN, E);

    // ---- layer 1: y1 = x@W1l (fp8), z1 = x@W1r + b1 (MFMA) ----
    mlp_mfma_kernel<64, 64, 64, 128, 0><<<(NN + 127) / 128, 256, 0, stream>>>(
        x, nullptr, W1l, W1r, b1, (unsigned char*)bufY, z1, NN);
    // D=64: G=4, EP=2 -> TPN=8, 32 nodes/block
    agg_mean_fp8_kernel<64, 2><<<(NN + 31) / 32, 256, 0, stream>>>(
        (const unsigned int*)bufY, row_ptr, ssrc, inv_deg, meanB, NN);

    // ---- layer 2: h1 = relu(mean1+z1) fused; y2 fp8, z2 (MFMA) ----
    mlp_mfma_kernel<64, 32, 32, 128, 1><<<(NN + 127) / 128, 256, 0, stream>>>(
        meanB, z1, W2l, W2r, b2, (unsigned char*)bufY, z2, NN);
    // D=32: G=2, EP=4 -> TPN=8, 32 nodes/block
    agg_mean_fp8_kernel<32, 4><<<(NN + 31) / 32, 256, 0, stream>>>(
        (const unsigned int*)bufY, row_ptr, ssrc, inv_deg, meanB, NN);

    // ---- layer 3: h2 = relu(mean2+z2) fused; y3 f32, z3; sigmoid fused ----
    mlp3_kernel<32><<<(NN + 255) / 256, 256, 0, stream>>>(
        meanB, z2, W3l, W3r, b3, bufY, z3, NN);
    agg_mean_d1_sig_kernel<<<(NN + 3) / 4, 256, 0, stream>>>(
        bufY, row_ptr, ssrc, inv_deg, z3, out, NN);
}